// Round 1
// baseline (785.350 us; speedup 1.0000x reference)
//
#include <hip/hip_runtime.h>
#include <hip/hip_bf16.h>

// GCN: embed -> (conv -> bn -> relu) x2 -> conv -> relu -> mean-pool -> linear
// H = 64 (one lane per channel), fp32 throughout.

#define HDIM 64

// ---------- tiny precompute: fold one-hot/numeric linears through Wg0 ----------
// M1[t][c] = sum_k W1[t][k]*Wg0[k][c]            (T x 64)
// M2[j][c] = sum_k W2[j][k]*Wg0[64+k][c]         (5 x 64)
// cvec[c]  = sum_k b1[k]*Wg0[k][c] + b2[k]*Wg0[64+k][c]
__global__ void precompute_mats(const float* __restrict__ W1, const float* __restrict__ b1,
                                const float* __restrict__ W2, const float* __restrict__ b2,
                                const float* __restrict__ Wg0,
                                float* __restrict__ M1, float* __restrict__ M2,
                                float* __restrict__ cvec, int T) {
    int tid = threadIdx.x;
    for (int idx = tid; idx < T * 64; idx += blockDim.x) {
        int t = idx >> 6, c = idx & 63;
        float a = 0.f;
        for (int k = 0; k < 64; ++k) a += W1[t * 64 + k] * Wg0[k * 64 + c];
        M1[idx] = a;
    }
    for (int idx = tid; idx < 5 * 64; idx += blockDim.x) {
        int j = idx >> 6, c = idx & 63;
        float a = 0.f;
        for (int k = 0; k < 64; ++k) a += W2[j * 64 + k] * Wg0[(64 + k) * 64 + c];
        M2[idx] = a;
    }
    for (int c = tid; c < 64; c += blockDim.x) {
        float a = 0.f;
        for (int k = 0; k < 64; ++k)
            a += b1[k] * Wg0[k * 64 + c] + b2[k] * Wg0[(64 + k) * 64 + c];
        cvec[c] = a;
    }
}

// ---------- node features -> h0 [N,64] ----------
__global__ void node_embed(const int* __restrict__ type_ids,
                           const float* __restrict__ f0, const float* __restrict__ f1,
                           const float* __restrict__ f2, const float* __restrict__ f3,
                           const float* __restrict__ f4,
                           const float* __restrict__ M1, const float* __restrict__ M2,
                           const float* __restrict__ cvec,
                           float* __restrict__ h, int n) {
    int i = blockIdx.x * (blockDim.x >> 6) + (threadIdx.x >> 6);
    int lane = threadIdx.x & 63;
    if (i >= n) return;
    int t = type_ids[i];
    float a = M1[t * 64 + lane] + cvec[lane];
    a += f0[i] * M2[0 * 64 + lane];
    a += f1[i] * M2[1 * 64 + lane];
    a += f2[i] * M2[2 * 64 + lane];
    a += f3[i] * M2[3 * 64 + lane];
    a += f4[i] * M2[4 * 64 + lane];
    h[i * 64 + lane] = a;
}

// ---------- degree / CSR build ----------
__global__ void count_deg(const int* __restrict__ dst, int* __restrict__ deg, int e) {
    int i = blockIdx.x * blockDim.x + threadIdx.x;
    if (i < e) atomicAdd(&deg[dst[i]], 1);
}

__global__ void compute_dinv(const int* __restrict__ deg, float* __restrict__ dinv, int n) {
    int i = blockIdx.x * blockDim.x + threadIdx.x;
    if (i < n) dinv[i] = rsqrtf((float)(deg[i] + 1));  // +1 self loop
}

// single-block inclusive-scan -> exclusive offsets. n up to ~50k, 1024 threads.
__global__ void scan_offsets(const int* __restrict__ deg, int* __restrict__ off, int n) {
    __shared__ int buf[1024];
    __shared__ int carry;
    if (threadIdx.x == 0) carry = 0;
    __syncthreads();
    for (int base = 0; base < n; base += 1024) {
        int i = base + threadIdx.x;
        int v = (i < n) ? deg[i] : 0;
        buf[threadIdx.x] = v;
        __syncthreads();
        for (int ofs = 1; ofs < 1024; ofs <<= 1) {
            int t = (threadIdx.x >= ofs) ? buf[threadIdx.x - ofs] : 0;
            __syncthreads();
            buf[threadIdx.x] += t;
            __syncthreads();
        }
        int incl = buf[threadIdx.x];
        int base_carry = carry;
        if (i < n) off[i + 1] = base_carry + incl;
        __syncthreads();
        if (threadIdx.x == 0) carry = base_carry + buf[1023];
        __syncthreads();
    }
    if (threadIdx.x == 0) off[0] = 0;
}

__global__ void init_cursor(const int* __restrict__ off, int* __restrict__ cursor, int n) {
    int i = blockIdx.x * blockDim.x + threadIdx.x;
    if (i < n) cursor[i] = off[i];
}

__global__ void fill_csr(const int* __restrict__ src, const int* __restrict__ dst,
                         const float* __restrict__ dinv, int* __restrict__ cursor,
                         int* __restrict__ csr_src, float* __restrict__ csr_w, int e) {
    int i = blockIdx.x * blockDim.x + threadIdx.x;
    if (i >= e) return;
    int s = src[i], d = dst[i];
    int pos = atomicAdd(&cursor[d], 1);
    csr_src[pos] = s;
    csr_w[pos] = dinv[s] * dinv[d];
}

// ---------- conv gather: out[n] = sum_in h[src]*w + h[n]*dinv^2 + bias ----------
__global__ void conv_gather(const float* __restrict__ h,
                            const int* __restrict__ off, const int* __restrict__ csr_src,
                            const float* __restrict__ csr_w, const float* __restrict__ dinv,
                            const float* __restrict__ bias, float* __restrict__ out, int n) {
    int i = blockIdx.x * (blockDim.x >> 6) + (threadIdx.x >> 6);
    int lane = threadIdx.x & 63;
    if (i >= n) return;
    int b = off[i], e = off[i + 1];
    float di = dinv[i];
    float acc = h[i * 64 + lane] * di * di;
    for (int k = b; k < e; ++k) {
        int s = csr_src[k];
        float w = csr_w[k];
        acc += h[s * 64 + lane] * w;
    }
    out[i * 64 + lane] = acc + bias[lane];
}

// ---------- batchnorm stats ----------
__global__ void bn_stats(const float* __restrict__ y, float* __restrict__ sums, int n) {
    int lane = threadIdx.x & 63;
    int w = threadIdx.x >> 6;
    int waves_per_blk = blockDim.x >> 6;
    float s = 0.f, ss = 0.f;
    for (int i = blockIdx.x * waves_per_blk + w; i < n; i += gridDim.x * waves_per_blk) {
        float v = y[i * 64 + lane];
        s += v;
        ss += v * v;
    }
    atomicAdd(&sums[lane], s);
    atomicAdd(&sums[64 + lane], ss);
}

__global__ void bn_finalize(const float* __restrict__ sums, const float* __restrict__ gamma,
                            const float* __restrict__ beta, float* __restrict__ scsh, int n) {
    int c = threadIdx.x;
    if (c < 64) {
        float mean = sums[c] / (float)n;
        float var = sums[64 + c] / (float)n - mean * mean;
        float sc = rsqrtf(var + 1e-5f) * gamma[c];
        scsh[c] = sc;
        scsh[64 + c] = beta[c] - mean * sc;
    }
}

// ---------- fused bn+relu+GEMM: h[n] = relu(y[n]*sc+sh) @ W ----------
__global__ void bn_relu_gemm(const float* __restrict__ y, const float* __restrict__ scsh,
                             const float* __restrict__ W, float* __restrict__ h, int n) {
    __shared__ float Wl[64 * 64];
    for (int i = threadIdx.x; i < 64 * 64; i += blockDim.x) Wl[i] = W[i];
    __syncthreads();
    int i = blockIdx.x * (blockDim.x >> 6) + (threadIdx.x >> 6);
    int lane = threadIdx.x & 63;
    if (i >= n) return;
    float v = y[i * 64 + lane];
    v = fmaxf(v * scsh[lane] + scsh[64 + lane], 0.f);
    float acc = 0.f;
#pragma unroll
    for (int k = 0; k < 64; ++k) {
        acc += __shfl(v, k, 64) * Wl[k * 64 + lane];
    }
    h[i * 64 + lane] = acc;
}

// ---------- relu + mean-pool accumulate ----------
__global__ void pool_kernel(const float* __restrict__ y, const int* __restrict__ batch,
                            float* __restrict__ pooled, int* __restrict__ cnt, int n) {
    int i = blockIdx.x * (blockDim.x >> 6) + (threadIdx.x >> 6);
    int lane = threadIdx.x & 63;
    if (i >= n) return;
    int g = batch[i];
    atomicAdd(&pooled[g * 64 + lane], fmaxf(y[i * 64 + lane], 0.f));
    if (lane == 0) atomicAdd(&cnt[g], 1);
}

// ---------- final: out[g] = (pooled[g]/cnt) @ Wout + bout ----------
__global__ void final_out(const float* __restrict__ pooled, const int* __restrict__ cnt,
                          const float* __restrict__ Wout, const float* __restrict__ bout,
                          float* __restrict__ out, int G) {
    int idx = blockIdx.x * blockDim.x + threadIdx.x;
    if (idx >= G * 4) return;
    int g = idx >> 2, o = idx & 3;
    float inv = 1.f / fmaxf((float)cnt[g], 1.f);
    float a = 0.f;
    for (int k = 0; k < 64; ++k) a += pooled[g * 64 + k] * Wout[k * 4 + o];
    out[idx] = a * inv + bout[o];
}

extern "C" void kernel_launch(void* const* d_in, const int* in_sizes, int n_in,
                              void* d_out, int out_size, void* d_ws, size_t ws_size,
                              hipStream_t stream) {
    const int N = in_sizes[0];
    const int E = in_sizes[6] / 2;
    const int T = in_sizes[8] / 64;
    const int G = out_size / 4;

    const int*   type_ids = (const int*)d_in[0];
    const float* fc   = (const float*)d_in[1];
    const float* fgm  = (const float*)d_in[2];
    const float* fpos = (const float*)d_in[3];
    const float* fr   = (const float*)d_in[4];
    const float* fvid = (const float*)d_in[5];
    const int*   ei   = (const int*)d_in[6];
    const int*   batch = (const int*)d_in[7];
    const float* W1 = (const float*)d_in[8];
    const float* b1 = (const float*)d_in[9];
    const float* W2 = (const float*)d_in[10];
    const float* b2 = (const float*)d_in[11];
    const float* Wg0 = (const float*)d_in[12];
    const float* bg0 = (const float*)d_in[13];
    const float* Wg1 = (const float*)d_in[14];
    const float* bg1 = (const float*)d_in[15];
    const float* Wg2 = (const float*)d_in[16];
    const float* bg2 = (const float*)d_in[17];
    const float* gam0 = (const float*)d_in[18];
    const float* bet0 = (const float*)d_in[19];
    const float* gam1 = (const float*)d_in[20];
    const float* bet1 = (const float*)d_in[21];
    const float* Wout = (const float*)d_in[22];
    const float* bout = (const float*)d_in[23];

    const int* e_src = ei;
    const int* e_dst = ei + E;

    // ---- workspace layout ----
    char* ws = (char*)d_ws;
    size_t o = 0;
    auto alloc = [&](size_t bytes) -> char* {
        char* p = ws + o;
        o += (bytes + 255) & ~(size_t)255;
        return p;
    };
    float* h       = (float*)alloc((size_t)N * 64 * 4);
    float* y       = (float*)alloc((size_t)N * 64 * 4);
    int*   deg     = (int*)alloc((size_t)N * 4);
    float* dinv    = (float*)alloc((size_t)N * 4);
    int*   off     = (int*)alloc((size_t)(N + 1) * 4);
    int*   cursor  = (int*)alloc((size_t)N * 4);
    int*   csr_src = (int*)alloc((size_t)E * 4);
    float* csr_w   = (float*)alloc((size_t)E * 4);
    float* sums0   = (float*)alloc(128 * 4);
    float* sums1   = (float*)alloc(128 * 4);
    float* scsh0   = (float*)alloc(128 * 4);
    float* scsh1   = (float*)alloc(128 * 4);
    float* pooled  = (float*)alloc((size_t)G * 64 * 4);
    int*   cnt     = (int*)alloc((size_t)G * 4);
    float* M1      = (float*)alloc((size_t)T * 64 * 4);
    float* M2      = (float*)alloc(5 * 64 * 4);
    float* cvec    = (float*)alloc(64 * 4);
    (void)ws_size;

    // zero-init accumulators (no cross-call state)
    hipMemsetAsync(deg, 0, (size_t)N * 4, stream);
    hipMemsetAsync(sums0, 0, 128 * 4, stream);
    hipMemsetAsync(sums1, 0, 128 * 4, stream);
    hipMemsetAsync(pooled, 0, (size_t)G * 64 * 4, stream);
    hipMemsetAsync(cnt, 0, (size_t)G * 4, stream);

    const int waves_per_blk = 4;                   // 256 threads
    const int nblk_nodes = (N + waves_per_blk - 1) / waves_per_blk;

    precompute_mats<<<1, 256, 0, stream>>>(W1, b1, W2, b2, Wg0, M1, M2, cvec, T);
    node_embed<<<nblk_nodes, 256, 0, stream>>>(type_ids, fc, fgm, fpos, fr, fvid, M1, M2, cvec, h, N);

    count_deg<<<(E + 255) / 256, 256, 0, stream>>>(e_dst, deg, E);
    compute_dinv<<<(N + 255) / 256, 256, 0, stream>>>(deg, dinv, N);
    scan_offsets<<<1, 1024, 0, stream>>>(deg, off, N);
    init_cursor<<<(N + 255) / 256, 256, 0, stream>>>(off, cursor, N);
    fill_csr<<<(E + 255) / 256, 256, 0, stream>>>(e_src, e_dst, dinv, cursor, csr_src, csr_w, E);

    // layer 0
    conv_gather<<<nblk_nodes, 256, 0, stream>>>(h, off, csr_src, csr_w, dinv, bg0, y, N);
    bn_stats<<<256, 256, 0, stream>>>(y, sums0, N);
    bn_finalize<<<1, 64, 0, stream>>>(sums0, gam0, bet0, scsh0, N);
    bn_relu_gemm<<<nblk_nodes, 256, 0, stream>>>(y, scsh0, Wg1, h, N);

    // layer 1
    conv_gather<<<nblk_nodes, 256, 0, stream>>>(h, off, csr_src, csr_w, dinv, bg1, y, N);
    bn_stats<<<256, 256, 0, stream>>>(y, sums1, N);
    bn_finalize<<<1, 64, 0, stream>>>(sums1, gam1, bet1, scsh1, N);
    bn_relu_gemm<<<nblk_nodes, 256, 0, stream>>>(y, scsh1, Wg2, h, N);

    // layer 2 (no bn)
    conv_gather<<<nblk_nodes, 256, 0, stream>>>(h, off, csr_src, csr_w, dinv, bg2, y, N);

    // relu + pool + output
    pool_kernel<<<nblk_nodes, 256, 0, stream>>>(y, batch, pooled, cnt, N);
    final_out<<<(G * 4 + 255) / 256, 256, 0, stream>>>(pooled, cnt, Wout, bout, (float*)d_out, G);
}

// Round 2
// 704.061 us; speedup vs baseline: 1.1155x; 1.1155x over previous
//
#include <hip/hip_runtime.h>
#include <hip/hip_bf16.h>

// GCN: embed -> (conv -> bn -> relu) x2 -> conv(+relu+pool fused) -> linear
// H = 64 (one lane per channel), fp32 throughout.

// ---------- tiny precompute: fold one-hot/numeric linears through Wg0 ----------
__global__ void precompute_mats(const float* __restrict__ W1, const float* __restrict__ b1,
                                const float* __restrict__ W2, const float* __restrict__ b2,
                                const float* __restrict__ Wg0,
                                float* __restrict__ M1, float* __restrict__ M2,
                                float* __restrict__ cvec, int T) {
    int tid = threadIdx.x;
    for (int idx = tid; idx < T * 64; idx += blockDim.x) {
        int t = idx >> 6, c = idx & 63;
        float a = 0.f;
        for (int k = 0; k < 64; ++k) a += W1[t * 64 + k] * Wg0[k * 64 + c];
        M1[idx] = a;
    }
    for (int idx = tid; idx < 5 * 64; idx += blockDim.x) {
        int j = idx >> 6, c = idx & 63;
        float a = 0.f;
        for (int k = 0; k < 64; ++k) a += W2[j * 64 + k] * Wg0[(64 + k) * 64 + c];
        M2[idx] = a;
    }
    for (int c = tid; c < 64; c += blockDim.x) {
        float a = 0.f;
        for (int k = 0; k < 64; ++k)
            a += b1[k] * Wg0[k * 64 + c] + b2[k] * Wg0[(64 + k) * 64 + c];
        cvec[c] = a;
    }
}

// ---------- node features -> h0 [N,64] ----------
__global__ void node_embed(const int* __restrict__ type_ids,
                           const float* __restrict__ f0, const float* __restrict__ f1,
                           const float* __restrict__ f2, const float* __restrict__ f3,
                           const float* __restrict__ f4,
                           const float* __restrict__ M1, const float* __restrict__ M2,
                           const float* __restrict__ cvec,
                           float* __restrict__ h, int n) {
    int i = blockIdx.x * (blockDim.x >> 6) + (threadIdx.x >> 6);
    int lane = threadIdx.x & 63;
    if (i >= n) return;
    int t = type_ids[i];
    float a = M1[t * 64 + lane] + cvec[lane];
    a += f0[i] * M2[0 * 64 + lane];
    a += f1[i] * M2[1 * 64 + lane];
    a += f2[i] * M2[2 * 64 + lane];
    a += f3[i] * M2[3 * 64 + lane];
    a += f4[i] * M2[4 * 64 + lane];
    h[i * 64 + lane] = a;
}

// ---------- degree / CSR build ----------
__global__ void count_deg(const int* __restrict__ dst, int* __restrict__ deg, int e) {
    int i = blockIdx.x * blockDim.x + threadIdx.x;
    if (i < e) atomicAdd(&deg[dst[i]], 1);
}

__global__ void compute_dinv(const int* __restrict__ deg, float* __restrict__ dinv, int n) {
    int i = blockIdx.x * blockDim.x + threadIdx.x;
    if (i < n) dinv[i] = rsqrtf((float)(deg[i] + 1));  // +1 self loop
}

// single-block scan -> exclusive offsets. shuffle-based, 3 barriers per 1024-tile.
__global__ void scan_offsets(const int* __restrict__ deg, int* __restrict__ off, int n) {
    __shared__ int wsum[16];
    __shared__ int wexcl[16];
    __shared__ int carry_s;
    const int tid = threadIdx.x;          // 1024 threads
    const int lane = tid & 63, w = tid >> 6;
    if (tid == 0) carry_s = 0;
    __syncthreads();
    for (int base = 0; base < n; base += 1024) {
        int i = base + tid;
        int v = (i < n) ? deg[i] : 0;
        int incl = v;
#pragma unroll
        for (int ofs = 1; ofs < 64; ofs <<= 1) {
            int t = __shfl_up(incl, (unsigned)ofs, 64);
            if (lane >= ofs) incl += t;
        }
        if (lane == 63) wsum[w] = incl;
        __syncthreads();
        if (w == 0 && lane < 16) {
            int s = wsum[lane];
            int sc = s;
#pragma unroll
            for (int ofs = 1; ofs < 16; ofs <<= 1) {
                int t = __shfl_up(sc, (unsigned)ofs, 64);
                if (lane >= ofs) sc += t;
            }
            wexcl[lane] = sc - s;
            if (lane == 15) wsum[15] = sc;  // block total
        }
        __syncthreads();
        int total = wsum[15];
        int carry = carry_s;
        if (i < n) off[i + 1] = carry + wexcl[w] + incl;
        __syncthreads();
        if (tid == 0) carry_s = carry + total;
        __syncthreads();
    }
    if (tid == 0) off[0] = 0;
}

__global__ void init_cursor(const int* __restrict__ off, int* __restrict__ cursor, int n) {
    int i = blockIdx.x * blockDim.x + threadIdx.x;
    if (i < n) cursor[i] = off[i];
}

__global__ void fill_csr(const int* __restrict__ src, const int* __restrict__ dst,
                         const float* __restrict__ dinv, int* __restrict__ cursor,
                         int* __restrict__ csr_src, float* __restrict__ csr_w, int e) {
    int i = blockIdx.x * blockDim.x + threadIdx.x;
    if (i >= e) return;
    int s = src[i], d = dst[i];
    int pos = atomicAdd(&cursor[d], 1);
    csr_src[pos] = s;
    csr_w[pos] = dinv[s] * dinv[d];
}

// ---------- conv gather: out[n] = sum_in h[src]*w + h[n]*dinv^2 + bias ----------
__global__ void conv_gather(const float* __restrict__ h,
                            const int* __restrict__ off, const int* __restrict__ csr_src,
                            const float* __restrict__ csr_w, const float* __restrict__ dinv,
                            const float* __restrict__ bias, float* __restrict__ out, int n) {
    int i = blockIdx.x * (blockDim.x >> 6) + (threadIdx.x >> 6);
    int lane = threadIdx.x & 63;
    if (i >= n) return;
    int b = off[i], e = off[i + 1];
    float di = dinv[i];
    float acc = h[i * 64 + lane] * di * di;
    for (int k = b; k < e; ++k) {
        int s = csr_src[k];
        float w = csr_w[k];
        acc += h[s * 64 + lane] * w;
    }
    out[i * 64 + lane] = acc + bias[lane];
}

// ---------- conv + relu + segmented mean-pool (layer 2), exploits sorted batch ----------
#define POOL_CHUNK 8
__global__ void conv_relu_pool(const float* __restrict__ h,
                               const int* __restrict__ off, const int* __restrict__ csr_src,
                               const float* __restrict__ csr_w, const float* __restrict__ dinv,
                               const float* __restrict__ bias, const int* __restrict__ batch,
                               float* __restrict__ pooled, int* __restrict__ cnt, int n) {
    int wave = blockIdx.x * (blockDim.x >> 6) + (threadIdx.x >> 6);
    int lane = threadIdx.x & 63;
    int start = wave * POOL_CHUNK;
    if (start >= n) return;
    int end = min(n, start + POOL_CHUNK);
    float bl = bias[lane];
    float accp = 0.f;
    int cur = batch[start];
    int cl = 0;
    for (int i = start; i < end; ++i) {
        int g = batch[i];
        if (g != cur) {  // wave-uniform branch (batch sorted, same for all lanes)
            atomicAdd(&pooled[cur * 64 + lane], accp);
            if (lane == 0) atomicAdd(&cnt[cur], cl);
            accp = 0.f; cl = 0; cur = g;
        }
        int b = off[i], e = off[i + 1];
        float di = dinv[i];
        float a = h[i * 64 + lane] * di * di;
        for (int k = b; k < e; ++k) {
            a += h[csr_src[k] * 64 + lane] * csr_w[k];
        }
        accp += fmaxf(a + bl, 0.f);
        ++cl;
    }
    atomicAdd(&pooled[cur * 64 + lane], accp);
    if (lane == 0) atomicAdd(&cnt[cur], cl);
}

// ---------- batchnorm stats: per-block partials (no atomics) ----------
__global__ void bn_stats(const float* __restrict__ y, float* __restrict__ partials, int n) {
    __shared__ float sh[4][128];
    int lane = threadIdx.x & 63;
    int w = threadIdx.x >> 6;
    int waves_per_blk = blockDim.x >> 6;
    float s = 0.f, ss = 0.f;
    for (int i = blockIdx.x * waves_per_blk + w; i < n; i += gridDim.x * waves_per_blk) {
        float v = y[i * 64 + lane];
        s += v;
        ss += v * v;
    }
    sh[w][lane] = s;
    sh[w][64 + lane] = ss;
    __syncthreads();
    if (threadIdx.x < 128) {
        float a = sh[0][threadIdx.x] + sh[1][threadIdx.x] + sh[2][threadIdx.x] + sh[3][threadIdx.x];
        partials[blockIdx.x * 128 + threadIdx.x] = a;
    }
}

__global__ void bn_finalize(const float* __restrict__ partials, int nblk,
                            const float* __restrict__ gamma, const float* __restrict__ beta,
                            float* __restrict__ scsh, int n) {
    __shared__ float sums[128];
    int j = threadIdx.x;  // 128 threads
    float a = 0.f;
    for (int b = 0; b < nblk; ++b) a += partials[b * 128 + j];
    sums[j] = a;
    __syncthreads();
    if (j < 64) {
        float mean = sums[j] / (float)n;
        float var = sums[64 + j] / (float)n - mean * mean;
        float sc = rsqrtf(var + 1e-5f) * gamma[j];
        scsh[j] = sc;
        scsh[64 + j] = beta[j] - mean * sc;
    }
}

// ---------- fused bn+relu+GEMM: h[n] = relu(y[n]*sc+sh) @ W ----------
__global__ void bn_relu_gemm(const float* __restrict__ y, const float* __restrict__ scsh,
                             const float* __restrict__ W, float* __restrict__ h, int n) {
    __shared__ float Wl[64 * 64];
    for (int i = threadIdx.x; i < 64 * 64; i += blockDim.x) Wl[i] = W[i];
    __syncthreads();
    int i = blockIdx.x * (blockDim.x >> 6) + (threadIdx.x >> 6);
    int lane = threadIdx.x & 63;
    if (i >= n) return;
    float v = y[i * 64 + lane];
    v = fmaxf(v * scsh[lane] + scsh[64 + lane], 0.f);
    float acc = 0.f;
#pragma unroll
    for (int k = 0; k < 64; ++k) {
        acc += __shfl(v, k, 64) * Wl[k * 64 + lane];
    }
    h[i * 64 + lane] = acc;
}

// ---------- final: out[g] = (pooled[g]/cnt) @ Wout + bout ----------
__global__ void final_out(const float* __restrict__ pooled, const int* __restrict__ cnt,
                          const float* __restrict__ Wout, const float* __restrict__ bout,
                          float* __restrict__ out, int G) {
    int idx = blockIdx.x * blockDim.x + threadIdx.x;
    if (idx >= G * 4) return;
    int g = idx >> 2, o = idx & 3;
    float inv = 1.f / fmaxf((float)cnt[g], 1.f);
    float a = 0.f;
    for (int k = 0; k < 64; ++k) a += pooled[g * 64 + k] * Wout[k * 4 + o];
    out[idx] = a * inv + bout[o];
}

extern "C" void kernel_launch(void* const* d_in, const int* in_sizes, int n_in,
                              void* d_out, int out_size, void* d_ws, size_t ws_size,
                              hipStream_t stream) {
    const int N = in_sizes[0];
    const int E = in_sizes[6] / 2;
    const int T = in_sizes[8] / 64;
    const int G = out_size / 4;

    const int*   type_ids = (const int*)d_in[0];
    const float* fc   = (const float*)d_in[1];
    const float* fgm  = (const float*)d_in[2];
    const float* fpos = (const float*)d_in[3];
    const float* fr   = (const float*)d_in[4];
    const float* fvid = (const float*)d_in[5];
    const int*   ei   = (const int*)d_in[6];
    const int*   batch = (const int*)d_in[7];
    const float* W1 = (const float*)d_in[8];
    const float* b1 = (const float*)d_in[9];
    const float* W2 = (const float*)d_in[10];
    const float* b2 = (const float*)d_in[11];
    const float* Wg0 = (const float*)d_in[12];
    const float* bg0 = (const float*)d_in[13];
    const float* Wg1 = (const float*)d_in[14];
    const float* bg1 = (const float*)d_in[15];
    const float* Wg2 = (const float*)d_in[16];
    const float* bg2 = (const float*)d_in[17];
    const float* gam0 = (const float*)d_in[18];
    const float* bet0 = (const float*)d_in[19];
    const float* gam1 = (const float*)d_in[20];
    const float* bet1 = (const float*)d_in[21];
    const float* Wout = (const float*)d_in[22];
    const float* bout = (const float*)d_in[23];

    const int* e_src = ei;
    const int* e_dst = ei + E;

    // ---- workspace layout ----
    char* ws = (char*)d_ws;
    size_t o = 0;
    auto alloc = [&](size_t bytes) -> char* {
        char* p = ws + o;
        o += (bytes + 255) & ~(size_t)255;
        return p;
    };
    const int NBLK_BN = 256;
    float* h        = (float*)alloc((size_t)N * 64 * 4);
    float* y        = (float*)alloc((size_t)N * 64 * 4);
    int*   deg      = (int*)alloc((size_t)N * 4);
    float* dinv     = (float*)alloc((size_t)N * 4);
    int*   off      = (int*)alloc((size_t)(N + 1) * 4);
    int*   cursor   = (int*)alloc((size_t)N * 4);
    int*   csr_src  = (int*)alloc((size_t)E * 4);
    float* csr_w    = (float*)alloc((size_t)E * 4);
    float* part0    = (float*)alloc((size_t)NBLK_BN * 128 * 4);
    float* part1    = (float*)alloc((size_t)NBLK_BN * 128 * 4);
    float* scsh0    = (float*)alloc(128 * 4);
    float* scsh1    = (float*)alloc(128 * 4);
    float* pooled   = (float*)alloc((size_t)G * 64 * 4);
    int*   cnt      = (int*)alloc((size_t)G * 4);
    float* M1       = (float*)alloc((size_t)T * 64 * 4);
    float* M2       = (float*)alloc(5 * 64 * 4);
    float* cvec     = (float*)alloc(64 * 4);
    (void)ws_size;

    hipMemsetAsync(deg, 0, (size_t)N * 4, stream);
    hipMemsetAsync(pooled, 0, (size_t)G * 64 * 4, stream);
    hipMemsetAsync(cnt, 0, (size_t)G * 4, stream);

    const int waves_per_blk = 4;                   // 256 threads
    const int nblk_nodes = (N + waves_per_blk - 1) / waves_per_blk;

    precompute_mats<<<1, 256, 0, stream>>>(W1, b1, W2, b2, Wg0, M1, M2, cvec, T);
    node_embed<<<nblk_nodes, 256, 0, stream>>>(type_ids, fc, fgm, fpos, fr, fvid, M1, M2, cvec, h, N);

    count_deg<<<(E + 255) / 256, 256, 0, stream>>>(e_dst, deg, E);
    compute_dinv<<<(N + 255) / 256, 256, 0, stream>>>(deg, dinv, N);
    scan_offsets<<<1, 1024, 0, stream>>>(deg, off, N);
    init_cursor<<<(N + 255) / 256, 256, 0, stream>>>(off, cursor, N);
    fill_csr<<<(E + 255) / 256, 256, 0, stream>>>(e_src, e_dst, dinv, cursor, csr_src, csr_w, E);

    // layer 0
    conv_gather<<<nblk_nodes, 256, 0, stream>>>(h, off, csr_src, csr_w, dinv, bg0, y, N);
    bn_stats<<<NBLK_BN, 256, 0, stream>>>(y, part0, N);
    bn_finalize<<<1, 128, 0, stream>>>(part0, NBLK_BN, gam0, bet0, scsh0, N);
    bn_relu_gemm<<<nblk_nodes, 256, 0, stream>>>(y, scsh0, Wg1, h, N);

    // layer 1
    conv_gather<<<nblk_nodes, 256, 0, stream>>>(h, off, csr_src, csr_w, dinv, bg1, y, N);
    bn_stats<<<NBLK_BN, 256, 0, stream>>>(y, part1, N);
    bn_finalize<<<1, 128, 0, stream>>>(part1, NBLK_BN, gam1, bet1, scsh1, N);
    bn_relu_gemm<<<nblk_nodes, 256, 0, stream>>>(y, scsh1, Wg2, h, N);

    // layer 2: conv + relu + segmented mean-pool fused
    {
        int waves = (N + POOL_CHUNK - 1) / POOL_CHUNK;
        int blocks = (waves + waves_per_blk - 1) / waves_per_blk;
        conv_relu_pool<<<blocks, 256, 0, stream>>>(h, off, csr_src, csr_w, dinv, bg2, batch,
                                                   pooled, cnt, N);
    }

    final_out<<<(G * 4 + 255) / 256, 256, 0, stream>>>(pooled, cnt, Wout, bout, (float*)d_out, G);
}

// Round 3
// 532.061 us; speedup vs baseline: 1.4761x; 1.3233x over previous
//
#include <hip/hip_runtime.h>
#include <hip/hip_bf16.h>

// GCN: embed -> (conv -> bn -> relu) x2 -> conv(+relu+pool fused) -> linear
// H = 64 (one lane per channel), fp32 throughout.
// R2: MLP-batched edge gathers (8 in flight), 3-phase parallel scan.

#define GATHER_BATCH 8

// ---------- tiny precompute: fold one-hot/numeric linears through Wg0 ----------
__global__ void precompute_mats(const float* __restrict__ W1, const float* __restrict__ b1,
                                const float* __restrict__ W2, const float* __restrict__ b2,
                                const float* __restrict__ Wg0,
                                float* __restrict__ M1, float* __restrict__ M2,
                                float* __restrict__ cvec, int T) {
    int tid = threadIdx.x;
    for (int idx = tid; idx < T * 64; idx += blockDim.x) {
        int t = idx >> 6, c = idx & 63;
        float a = 0.f;
        for (int k = 0; k < 64; ++k) a += W1[t * 64 + k] * Wg0[k * 64 + c];
        M1[idx] = a;
    }
    for (int idx = tid; idx < 5 * 64; idx += blockDim.x) {
        int j = idx >> 6, c = idx & 63;
        float a = 0.f;
        for (int k = 0; k < 64; ++k) a += W2[j * 64 + k] * Wg0[(64 + k) * 64 + c];
        M2[idx] = a;
    }
    for (int c = tid; c < 64; c += blockDim.x) {
        float a = 0.f;
        for (int k = 0; k < 64; ++k)
            a += b1[k] * Wg0[k * 64 + c] + b2[k] * Wg0[(64 + k) * 64 + c];
        cvec[c] = a;
    }
}

// ---------- node features -> h0 [N,64] ----------
__global__ void node_embed(const int* __restrict__ type_ids,
                           const float* __restrict__ f0, const float* __restrict__ f1,
                           const float* __restrict__ f2, const float* __restrict__ f3,
                           const float* __restrict__ f4,
                           const float* __restrict__ M1, const float* __restrict__ M2,
                           const float* __restrict__ cvec,
                           float* __restrict__ h, int n) {
    int i = blockIdx.x * (blockDim.x >> 6) + (threadIdx.x >> 6);
    int lane = threadIdx.x & 63;
    if (i >= n) return;
    int t = type_ids[i];
    float a = M1[t * 64 + lane] + cvec[lane];
    a += f0[i] * M2[0 * 64 + lane];
    a += f1[i] * M2[1 * 64 + lane];
    a += f2[i] * M2[2 * 64 + lane];
    a += f3[i] * M2[3 * 64 + lane];
    a += f4[i] * M2[4 * 64 + lane];
    h[i * 64 + lane] = a;
}

// ---------- degree / CSR build ----------
__global__ void count_deg(const int* __restrict__ dst, int* __restrict__ deg, int e) {
    int i = blockIdx.x * blockDim.x + threadIdx.x;
    if (i < e) atomicAdd(&deg[dst[i]], 1);
}

__global__ void compute_dinv(const int* __restrict__ deg, float* __restrict__ dinv, int n) {
    int i = blockIdx.x * blockDim.x + threadIdx.x;
    if (i < n) dinv[i] = rsqrtf((float)(deg[i] + 1));  // +1 self loop
}

// ---------- 3-phase scan: local tile scan -> tile-sum scan -> add ----------
#define SCAN_TILE 1024
// phase 1: each block (1024 thr) scans one tile, writes local inclusive + tile total
__global__ void scan_local(const int* __restrict__ deg, int* __restrict__ loc,
                           int* __restrict__ tilesum, int n) {
    __shared__ int wsum[16];
    __shared__ int wexcl[16];
    const int tid = threadIdx.x;
    const int lane = tid & 63, w = tid >> 6;
    int i = blockIdx.x * SCAN_TILE + tid;
    int v = (i < n) ? deg[i] : 0;
    int incl = v;
#pragma unroll
    for (int ofs = 1; ofs < 64; ofs <<= 1) {
        int t = __shfl_up(incl, (unsigned)ofs, 64);
        if (lane >= ofs) incl += t;
    }
    if (lane == 63) wsum[w] = incl;
    __syncthreads();
    if (w == 0 && lane < 16) {
        int s = wsum[lane];
        int sc = s;
#pragma unroll
        for (int ofs = 1; ofs < 16; ofs <<= 1) {
            int t = __shfl_up(sc, (unsigned)ofs, 64);
            if (lane >= ofs) sc += t;
        }
        wexcl[lane] = sc - s;
        if (lane == 15) wsum[15] = sc;
    }
    __syncthreads();
    if (i < n) loc[i] = wexcl[w] + incl;
    if (tid == 0) tilesum[blockIdx.x] = wsum[15];
}

// phase 2: single wave scans tile sums (numTiles <= 64) -> exclusive tile offsets
__global__ void scan_tiles(int* __restrict__ tilesum, int* __restrict__ tileoff, int nt) {
    int lane = threadIdx.x;
    int v = (lane < nt) ? tilesum[lane] : 0;
    int incl = v;
#pragma unroll
    for (int ofs = 1; ofs < 64; ofs <<= 1) {
        int t = __shfl_up(incl, (unsigned)ofs, 64);
        if (lane >= ofs) incl += t;
    }
    if (lane < nt) tileoff[lane] = incl - v;
}

// phase 3: off[i+1] = tileoff[tile] + loc[i]; cursor[i] = off[i]; off[0]=0
__global__ void scan_add(const int* __restrict__ loc, const int* __restrict__ tileoff,
                         int* __restrict__ off, int* __restrict__ cursor, int n) {
    int i = blockIdx.x * blockDim.x + threadIdx.x;
    if (i >= n) return;
    int val = tileoff[i / SCAN_TILE] + loc[i];
    off[i + 1] = val;
    if (i + 1 < n) cursor[i + 1] = val;
    if (i == 0) { off[0] = 0; cursor[0] = 0; }
}

__global__ void fill_csr(const int* __restrict__ src, const int* __restrict__ dst,
                         const float* __restrict__ dinv, int* __restrict__ cursor,
                         int* __restrict__ csr_src, float* __restrict__ csr_w, int e) {
    int i = blockIdx.x * blockDim.x + threadIdx.x;
    if (i >= e) return;
    int s = src[i], d = dst[i];
    int pos = atomicAdd(&cursor[d], 1);
    csr_src[pos] = s;
    csr_w[pos] = dinv[s] * dinv[d];
}

// ---------- conv gather (MLP-batched): out = sum h[src]*w + h[i]*dinv^2 + bias ----------
__global__ void conv_gather(const float* __restrict__ h,
                            const int* __restrict__ off, const int* __restrict__ csr_src,
                            const float* __restrict__ csr_w, const float* __restrict__ dinv,
                            const float* __restrict__ bias, float* __restrict__ out, int n) {
    int i = blockIdx.x * (blockDim.x >> 6) + (threadIdx.x >> 6);
    int lane = threadIdx.x & 63;
    if (i >= n) return;
    int b = off[i], e = off[i + 1];
    float di = dinv[i];
    float acc = h[i * 64 + lane] * di * di;
    for (int k = b; k < e; k += GATHER_BATCH) {
        int   s[GATHER_BATCH];
        float w[GATHER_BATCH];
        float v[GATHER_BATCH];
#pragma unroll
        for (int u = 0; u < GATHER_BATCH; ++u) {
            int kk = k + u;
            bool ok = kk < e;
            s[u] = ok ? csr_src[kk] : i;
            w[u] = ok ? csr_w[kk] : 0.f;
        }
#pragma unroll
        for (int u = 0; u < GATHER_BATCH; ++u) v[u] = h[s[u] * 64 + lane];
#pragma unroll
        for (int u = 0; u < GATHER_BATCH; ++u) acc += v[u] * w[u];
    }
    out[i * 64 + lane] = acc + bias[lane];
}

// ---------- conv + relu + segmented mean-pool (layer 2), exploits sorted batch ----------
#define POOL_CHUNK 4
__global__ void conv_relu_pool(const float* __restrict__ h,
                               const int* __restrict__ off, const int* __restrict__ csr_src,
                               const float* __restrict__ csr_w, const float* __restrict__ dinv,
                               const float* __restrict__ bias, const int* __restrict__ batch,
                               float* __restrict__ pooled, int* __restrict__ cnt, int n) {
    int wave = blockIdx.x * (blockDim.x >> 6) + (threadIdx.x >> 6);
    int lane = threadIdx.x & 63;
    int start = wave * POOL_CHUNK;
    if (start >= n) return;
    int end = min(n, start + POOL_CHUNK);
    float bl = bias[lane];
    float accp = 0.f;
    int cur = batch[start];
    int cl = 0;
    for (int i = start; i < end; ++i) {
        int g = batch[i];
        if (g != cur) {  // wave-uniform (batch sorted)
            atomicAdd(&pooled[cur * 64 + lane], accp);
            if (lane == 0) atomicAdd(&cnt[cur], cl);
            accp = 0.f; cl = 0; cur = g;
        }
        int b = off[i], e = off[i + 1];
        float di = dinv[i];
        float a = h[i * 64 + lane] * di * di;
        for (int k = b; k < e; k += GATHER_BATCH) {
            int   s[GATHER_BATCH];
            float w[GATHER_BATCH];
            float v[GATHER_BATCH];
#pragma unroll
            for (int u = 0; u < GATHER_BATCH; ++u) {
                int kk = k + u;
                bool ok = kk < e;
                s[u] = ok ? csr_src[kk] : i;
                w[u] = ok ? csr_w[kk] : 0.f;
            }
#pragma unroll
            for (int u = 0; u < GATHER_BATCH; ++u) v[u] = h[s[u] * 64 + lane];
#pragma unroll
            for (int u = 0; u < GATHER_BATCH; ++u) a += v[u] * w[u];
        }
        accp += fmaxf(a + bl, 0.f);
        ++cl;
    }
    atomicAdd(&pooled[cur * 64 + lane], accp);
    if (lane == 0) atomicAdd(&cnt[cur], cl);
}

// ---------- batchnorm stats: per-block partials (no atomics) ----------
__global__ void bn_stats(const float* __restrict__ y, float* __restrict__ partials, int n) {
    __shared__ float sh[4][128];
    int lane = threadIdx.x & 63;
    int w = threadIdx.x >> 6;
    int waves_per_blk = blockDim.x >> 6;
    float s = 0.f, ss = 0.f;
    for (int i = blockIdx.x * waves_per_blk + w; i < n; i += gridDim.x * waves_per_blk) {
        float v = y[i * 64 + lane];
        s += v;
        ss += v * v;
    }
    sh[w][lane] = s;
    sh[w][64 + lane] = ss;
    __syncthreads();
    if (threadIdx.x < 128) {
        float a = sh[0][threadIdx.x] + sh[1][threadIdx.x] + sh[2][threadIdx.x] + sh[3][threadIdx.x];
        partials[blockIdx.x * 128 + threadIdx.x] = a;
    }
}

__global__ void bn_finalize(const float* __restrict__ partials, int nblk,
                            const float* __restrict__ gamma, const float* __restrict__ beta,
                            float* __restrict__ scsh, int n) {
    __shared__ float sums[128];
    int j = threadIdx.x;  // 128 threads
    float a = 0.f;
    for (int b = 0; b < nblk; ++b) a += partials[b * 128 + j];
    sums[j] = a;
    __syncthreads();
    if (j < 64) {
        float mean = sums[j] / (float)n;
        float var = sums[64 + j] / (float)n - mean * mean;
        float sc = rsqrtf(var + 1e-5f) * gamma[j];
        scsh[j] = sc;
        scsh[64 + j] = beta[j] - mean * sc;
    }
}

// ---------- fused bn+relu+GEMM: h[n] = relu(y[n]*sc+sh) @ W ----------
__global__ void bn_relu_gemm(const float* __restrict__ y, const float* __restrict__ scsh,
                             const float* __restrict__ W, float* __restrict__ h, int n) {
    __shared__ float Wl[64 * 64];
    for (int i = threadIdx.x; i < 64 * 64; i += blockDim.x) Wl[i] = W[i];
    __syncthreads();
    int i = blockIdx.x * (blockDim.x >> 6) + (threadIdx.x >> 6);
    int lane = threadIdx.x & 63;
    if (i >= n) return;
    float v = y[i * 64 + lane];
    v = fmaxf(v * scsh[lane] + scsh[64 + lane], 0.f);
    float acc = 0.f;
#pragma unroll
    for (int k = 0; k < 64; ++k) {
        acc += __shfl(v, k, 64) * Wl[k * 64 + lane];
    }
    h[i * 64 + lane] = acc;
}

// ---------- final: out[g] = (pooled[g]/cnt) @ Wout + bout ----------
__global__ void final_out(const float* __restrict__ pooled, const int* __restrict__ cnt,
                          const float* __restrict__ Wout, const float* __restrict__ bout,
                          float* __restrict__ out, int G) {
    int idx = blockIdx.x * blockDim.x + threadIdx.x;
    if (idx >= G * 4) return;
    int g = idx >> 2, o = idx & 3;
    float inv = 1.f / fmaxf((float)cnt[g], 1.f);
    float a = 0.f;
    for (int k = 0; k < 64; ++k) a += pooled[g * 64 + k] * Wout[k * 4 + o];
    out[idx] = a * inv + bout[o];
}

extern "C" void kernel_launch(void* const* d_in, const int* in_sizes, int n_in,
                              void* d_out, int out_size, void* d_ws, size_t ws_size,
                              hipStream_t stream) {
    const int N = in_sizes[0];
    const int E = in_sizes[6] / 2;
    const int T = in_sizes[8] / 64;
    const int G = out_size / 4;

    const int*   type_ids = (const int*)d_in[0];
    const float* fc   = (const float*)d_in[1];
    const float* fgm  = (const float*)d_in[2];
    const float* fpos = (const float*)d_in[3];
    const float* fr   = (const float*)d_in[4];
    const float* fvid = (const float*)d_in[5];
    const int*   ei   = (const int*)d_in[6];
    const int*   batch = (const int*)d_in[7];
    const float* W1 = (const float*)d_in[8];
    const float* b1 = (const float*)d_in[9];
    const float* W2 = (const float*)d_in[10];
    const float* b2 = (const float*)d_in[11];
    const float* Wg0 = (const float*)d_in[12];
    const float* bg0 = (const float*)d_in[13];
    const float* Wg1 = (const float*)d_in[14];
    const float* bg1 = (const float*)d_in[15];
    const float* Wg2 = (const float*)d_in[16];
    const float* bg2 = (const float*)d_in[17];
    const float* gam0 = (const float*)d_in[18];
    const float* bet0 = (const float*)d_in[19];
    const float* gam1 = (const float*)d_in[20];
    const float* bet1 = (const float*)d_in[21];
    const float* Wout = (const float*)d_in[22];
    const float* bout = (const float*)d_in[23];

    const int* e_src = ei;
    const int* e_dst = ei + E;

    // ---- workspace layout ----
    char* ws = (char*)d_ws;
    size_t o = 0;
    auto alloc = [&](size_t bytes) -> char* {
        char* p = ws + o;
        o += (bytes + 255) & ~(size_t)255;
        return p;
    };
    const int NBLK_BN = 256;
    const int NTILES = (N + SCAN_TILE - 1) / SCAN_TILE;
    float* h        = (float*)alloc((size_t)N * 64 * 4);
    float* y        = (float*)alloc((size_t)N * 64 * 4);
    int*   deg      = (int*)alloc((size_t)N * 4);
    float* dinv     = (float*)alloc((size_t)N * 4);
    int*   off      = (int*)alloc((size_t)(N + 1) * 4);
    int*   cursor   = (int*)alloc((size_t)N * 4);
    int*   loc      = (int*)alloc((size_t)N * 4);
    int*   tilesum  = (int*)alloc((size_t)NTILES * 4);
    int*   tileoff  = (int*)alloc((size_t)NTILES * 4);
    int*   csr_src  = (int*)alloc((size_t)E * 4);
    float* csr_w    = (float*)alloc((size_t)E * 4);
    float* part0    = (float*)alloc((size_t)NBLK_BN * 128 * 4);
    float* part1    = (float*)alloc((size_t)NBLK_BN * 128 * 4);
    float* scsh0    = (float*)alloc(128 * 4);
    float* scsh1    = (float*)alloc(128 * 4);
    float* pooled   = (float*)alloc((size_t)G * 64 * 4);
    int*   cnt      = (int*)alloc((size_t)G * 4);
    float* M1       = (float*)alloc((size_t)T * 64 * 4);
    float* M2       = (float*)alloc(5 * 64 * 4);
    float* cvec     = (float*)alloc(64 * 4);
    (void)ws_size;

    hipMemsetAsync(deg, 0, (size_t)N * 4, stream);
    hipMemsetAsync(pooled, 0, (size_t)G * 64 * 4, stream);
    hipMemsetAsync(cnt, 0, (size_t)G * 4, stream);

    const int waves_per_blk = 4;                   // 256 threads
    const int nblk_nodes = (N + waves_per_blk - 1) / waves_per_blk;

    precompute_mats<<<1, 256, 0, stream>>>(W1, b1, W2, b2, Wg0, M1, M2, cvec, T);
    node_embed<<<nblk_nodes, 256, 0, stream>>>(type_ids, fc, fgm, fpos, fr, fvid, M1, M2, cvec, h, N);

    count_deg<<<(E + 255) / 256, 256, 0, stream>>>(e_dst, deg, E);
    compute_dinv<<<(N + 255) / 256, 256, 0, stream>>>(deg, dinv, N);
    scan_local<<<NTILES, SCAN_TILE, 0, stream>>>(deg, loc, tilesum, N);
    scan_tiles<<<1, 64, 0, stream>>>(tilesum, tileoff, NTILES);
    scan_add<<<(N + 255) / 256, 256, 0, stream>>>(loc, tileoff, off, cursor, N);
    fill_csr<<<(E + 255) / 256, 256, 0, stream>>>(e_src, e_dst, dinv, cursor, csr_src, csr_w, E);

    // layer 0
    conv_gather<<<nblk_nodes, 256, 0, stream>>>(h, off, csr_src, csr_w, dinv, bg0, y, N);
    bn_stats<<<NBLK_BN, 256, 0, stream>>>(y, part0, N);
    bn_finalize<<<1, 128, 0, stream>>>(part0, NBLK_BN, gam0, bet0, scsh0, N);
    bn_relu_gemm<<<nblk_nodes, 256, 0, stream>>>(y, scsh0, Wg1, h, N);

    // layer 1
    conv_gather<<<nblk_nodes, 256, 0, stream>>>(h, off, csr_src, csr_w, dinv, bg1, y, N);
    bn_stats<<<NBLK_BN, 256, 0, stream>>>(y, part1, N);
    bn_finalize<<<1, 128, 0, stream>>>(part1, NBLK_BN, gam1, bet1, scsh1, N);
    bn_relu_gemm<<<nblk_nodes, 256, 0, stream>>>(y, scsh1, Wg2, h, N);

    // layer 2: conv + relu + segmented mean-pool fused
    {
        int waves = (N + POOL_CHUNK - 1) / POOL_CHUNK;
        int blocks = (waves + waves_per_blk - 1) / waves_per_blk;
        conv_relu_pool<<<blocks, 256, 0, stream>>>(h, off, csr_src, csr_w, dinv, bg2, batch,
                                                   pooled, cnt, N);
    }

    final_out<<<(G * 4 + 255) / 256, 256, 0, stream>>>(pooled, cnt, Wout, bout, (float*)d_out, G);
}